// Round 21
// baseline (358.896 us; speedup 1.0000x reference)
//
#include <hip/hip_runtime.h>
#include <hip/hip_bf16.h>
#include <hip/hip_cooperative_groups.h>

namespace cg = cooperative_groups;

#define CC 256
#define CMM 32
#define KW 7
#define KK 49
#define PADW 3
#define HH 56
#define WW 56
#define LL 3136   // 56*56
#define BB 2
#define MM 8
#define MIDW 16

typedef __attribute__((ext_vector_type(8))) short bf16x8;
typedef __attribute__((ext_vector_type(4))) float f32x4;
typedef __attribute__((ext_vector_type(8))) unsigned short us8_t;

__device__ inline short bfr(float f) {   // f32 -> bf16 bits, RNE
  unsigned int u = __builtin_bit_cast(unsigned int, f);
  u += 0x7fffu + ((u >> 16) & 1u);
  return (short)(u >> 16);
}
__device__ inline float bf2f(short h) {
  return __builtin_bit_cast(float, ((unsigned int)(unsigned short)h) << 16);
}
__device__ inline float ubits(unsigned int u) {
  return __builtin_bit_cast(float, u);
}

// ================= fused cooperative kernel =================
// phase1 kq (392 blocks) -> phase2 attn (896) -> phase3 fconv (784).
// __launch_bounds__(256,4): cap VGPR at 128 so 4 blocks/CU co-reside
// (896 <= 1024 co-residency capacity). LDS union 17 KB.
__global__ void __launch_bounds__(256, 4) fused_kernel(
    const float* __restrict__ x,
    const float* __restrict__ k_w, const float* __restrict__ k_b,
    const float* __restrict__ q_w, const float* __restrict__ q_b,
    const float* __restrict__ gp_w1, const float* __restrict__ gp_b1,
    const float* __restrict__ gp_w2, const float* __restrict__ gp_b2,
    const float* __restrict__ f_w, const float* __restrict__ f_b,
    float* __restrict__ km, float* __restrict__ qm,
    unsigned short* __restrict__ pre, float* __restrict__ out) {
  cg::grid_group grid = cg::this_grid();
  __shared__ __align__(16) unsigned char shraw[17408];
  int t = threadIdx.x;
  int bx = blockIdx.x;
  int lane = t & 63;
  int w = t >> 6;
  int l15 = lane & 15;
  int hi = lane >> 4;
  const float LOG2E = 1.44269504f;

  // ---------------- Phase 1: kq ----------------
  if (bx < 392) {
    auto bsT = reinterpret_cast<unsigned short (*)[264]>(shraw);  // [16][264]
    int pxt = bx % 196;
    int b = bx / 196;
    int px0 = pxt * 16;

    int oc_a = w * 16 + l15;
    const float* wrow = ((oc_a < CMM) ? (k_w + (size_t)oc_a * CC)
                                      : (q_w + (size_t)(oc_a - CMM) * CC)) + hi * 8;
    bf16x8 ah[8], al[8];
    #pragma unroll
    for (int s = 0; s < 8; ++s) {
      f32x4 w0 = *(const f32x4*)(wrow + s * 32);
      f32x4 w1 = *(const f32x4*)(wrow + s * 32 + 4);
      bf16x8 h, l;
      #pragma unroll
      for (int j = 0; j < 4; ++j) {
        short hb0 = bfr(w0[j]); h[j] = hb0;     l[j] = bfr(w0[j] - bf2f(hb0));
        short hb1 = bfr(w1[j]); h[j + 4] = hb1; l[j + 4] = bfr(w1[j] - bf2f(hb1));
      }
      ah[s] = h; al[s] = l;
    }

    int spx = t & 15;
    int c0s = (t >> 4) * 16;
    const float* xg = x + (size_t)b * CC * LL + px0 + spx;
    float fv[16];
    #pragma unroll
    for (int j = 0; j < 16; ++j) fv[j] = xg[(size_t)(c0s + j) * LL];
    us8_t h0, h1;
    #pragma unroll
    for (int j = 0; j < 8; ++j) {
      h0[j] = (unsigned short)bfr(fv[j]);
      h1[j] = (unsigned short)bfr(fv[8 + j]);
    }
    *(us8_t*)&bsT[spx][c0s]     = h0;
    *(us8_t*)&bsT[spx][c0s + 8] = h1;
    __syncthreads();

    f32x4 acc = {0.f, 0.f, 0.f, 0.f};
    #pragma unroll
    for (int s = 0; s < 8; ++s) {
      bf16x8 bv = *(const bf16x8*)&bsT[l15][s * 32 + hi * 8];
      acc = __builtin_amdgcn_mfma_f32_16x16x32_bf16(ah[s], bv, acc, 0, 0, 0);
      acc = __builtin_amdgcn_mfma_f32_16x16x32_bf16(al[s], bv, acc, 0, 0, 0);
    }
    #pragma unroll
    for (int rr = 0; rr < 4; ++rr) {
      int oc = w * 16 + hi * 4 + rr;
      int px = px0 + l15;
      if (oc < CMM)
        km[((size_t)b * CMM + oc) * LL + px] = acc[rr] + k_b[oc];
      else
        qm[((size_t)b * CMM + (oc - CMM)) * LL + px] = acc[rr] + q_b[oc - CMM];
    }
  }

  grid.sync();

  // ---------------- Phase 2: attn ----------------
  {
    auto xlo = reinterpret_cast<unsigned int (*)[64][2]>(shraw);          // [10][64][2]
    auto xhi = reinterpret_cast<unsigned int (*)[64][2]>(shraw + 5120);
    auto ks  = reinterpret_cast<float (*)[64]>(shraw + 10240);            // [10][64]
    auto gs2 = reinterpret_cast<float*>(shraw + 12800);                   // [49]

    int band = bx % 14;
    int cm = (bx / 14) % 32;
    int b = bx / 448;
    int y0 = band * 4;

    if (t < KK) {
      int i = t / KW, j = t % KW;
      float xpos = (float)(j - PADW), ypos = (float)(PADW - i);
      float a = gp_b2[cm];
      #pragma unroll
      for (int m = 0; m < MIDW; ++m) {
        float h = fmaxf(gp_w1[2 * m] * xpos + gp_w1[2 * m + 1] * ypos + gp_b1[m], 0.f);
        a = fmaf(gp_w2[cm * MIDW + m], h, a);
      }
      gs2[t] = a * LOG2E;
    }
    float kb_cm = k_b[cm];
    const float* kmb = km + ((size_t)b * CMM + cm) * LL;
    for (int e = t; e < 640; e += 256) {
      int ri = e >> 6, cl = e & 63;
      int rp = y0 + ri;
      bool inner = (rp >= PADW && rp < PADW + HH && cl >= PADW && cl < PADW + WW);
      ks[ri][cl] = inner ? kmb[(rp - PADW) * WW + (cl - PADW)] : kb_cm;
    }
    const float* xg = x + (size_t)b * CC * LL;
    for (int e = t; e < 640; e += 256) {
      int ri = e >> 6, cl = e & 63;
      int ir = y0 - PADW + ri;
      int ic = cl - PADW;
      bool ok = (ir >= 0 && ir < HH && ic >= 0 && ic < WW);
      int off = ok ? (ir * WW + ic) : 0;
      unsigned int pk[4];
      #pragma unroll
      for (int mp = 0; mp < 4; ++mp) {
        float v0 = ok ? xg[(size_t)((2 * mp) * CMM + cm) * LL + off] : 0.f;
        float v1 = ok ? xg[(size_t)((2 * mp + 1) * CMM + cm) * LL + off] : 0.f;
        pk[mp] = (unsigned int)(unsigned short)bfr(v0)
               | ((unsigned int)(unsigned short)bfr(v1) << 16);
      }
      *(uint2*)&xlo[ri][cl][0] = make_uint2(pk[0], pk[1]);
      *(uint2*)&xhi[ri][cl][0] = make_uint2(pk[2], pk[3]);
    }
    __syncthreads();

    int c = lane;
    int y = y0 + w;
    int ce = (c < WW) ? c : (WW - 1);
    bool act = (c < WW);
    float qc = qm[((size_t)b * CMM + cm) * LL + y * WW + ce] * LOG2E;

    float acc[8] = {0.f, 0.f, 0.f, 0.f, 0.f, 0.f, 0.f, 0.f};
    #pragma unroll
    for (int i = 0; i < KW; ++i) {
      int row = w + i;
      float s[KW];
      float sum = 0.f;
      #pragma unroll
      for (int j = 0; j < KW; ++j) {
        s[j] = exp2f(fmaf(ks[row][ce + j], qc, gs2[i * KW + j]));
        sum += s[j];
      }
      float inv = __builtin_amdgcn_rcpf(sum);
      #pragma unroll
      for (int j = 0; j < KW; ++j) {
        float wj = s[j] * inv;
        uint2 lo2 = *(const uint2*)&xlo[row][ce + j][0];
        uint2 hi2 = *(const uint2*)&xhi[row][ce + j][0];
        acc[0] = fmaf(wj, ubits(lo2.x << 16), acc[0]);
        acc[1] = fmaf(wj, ubits(lo2.x & 0xffff0000u), acc[1]);
        acc[2] = fmaf(wj, ubits(lo2.y << 16), acc[2]);
        acc[3] = fmaf(wj, ubits(lo2.y & 0xffff0000u), acc[3]);
        acc[4] = fmaf(wj, ubits(hi2.x << 16), acc[4]);
        acc[5] = fmaf(wj, ubits(hi2.x & 0xffff0000u), acc[5]);
        acc[6] = fmaf(wj, ubits(hi2.y << 16), acc[6]);
        acc[7] = fmaf(wj, ubits(hi2.y & 0xffff0000u), acc[7]);
      }
    }
    if (act) {
      #pragma unroll
      for (int m = 0; m < 8; ++m)
        pre[((size_t)b * CC + (m * CMM + cm)) * LL + y * WW + c] =
            (unsigned short)bfr(acc[m]);
    }
  }

  grid.sync();

  // ---------------- Phase 3: fconv ----------------
  if (bx < 784) {
    auto bsT = reinterpret_cast<unsigned short (*)[264]>(shraw);  // [32][264]
    int pxt = bx % 98;
    int ocg = (bx / 98) % 4;
    int b = bx / 392;
    int px0 = pxt * 32;
    int oc0 = ocg * 64;

    bf16x8 af[8];
    const float* wrow = f_w + (size_t)(oc0 + w * 16 + l15) * CC + hi * 8;
    #pragma unroll
    for (int s = 0; s < 8; ++s) {
      f32x4 w0 = *(const f32x4*)(wrow + s * 32);
      f32x4 w1 = *(const f32x4*)(wrow + s * 32 + 4);
      bf16x8 a;
      #pragma unroll
      for (int j = 0; j < 4; ++j) { a[j] = bfr(w0[j]); a[j + 4] = bfr(w1[j]); }
      af[s] = a;
    }

    int spx = t & 31;
    int c0s = (t >> 5) * 32;
    const unsigned short* pg = pre + (size_t)b * CC * LL + px0 + spx;
    unsigned short uv[32];
    #pragma unroll
    for (int j = 0; j < 32; ++j) uv[j] = pg[(size_t)(c0s + j) * LL];
    #pragma unroll
    for (int qq = 0; qq < 4; ++qq) {
      us8_t hv;
      #pragma unroll
      for (int j = 0; j < 8; ++j) hv[j] = uv[qq * 8 + j];
      *(us8_t*)&bsT[spx][c0s + qq * 8] = hv;
    }
    __syncthreads();

    f32x4 acc[2];
    #pragma unroll
    for (int q = 0; q < 2; ++q) acc[q] = {0.f, 0.f, 0.f, 0.f};
    #pragma unroll
    for (int s = 0; s < 8; ++s) {
      #pragma unroll
      for (int q = 0; q < 2; ++q) {
        bf16x8 bv = *(const bf16x8*)&bsT[q * 16 + l15][s * 32 + hi * 8];
        acc[q] = __builtin_amdgcn_mfma_f32_16x16x32_bf16(af[s], bv, acc[q], 0, 0, 0);
      }
    }
    #pragma unroll
    for (int q = 0; q < 2; ++q) {
      #pragma unroll
      for (int rr = 0; rr < 4; ++rr) {
        int oc = oc0 + w * 16 + hi * 4 + rr;
        out[((size_t)b * CC + oc) * LL + px0 + q * 16 + l15] = acc[q][rr] + f_b[oc];
      }
    }
  }
}

// ================= fallback kernels (R18, verbatim) =================
__global__ void __launch_bounds__(256) kq_kernel(
    const float* __restrict__ x,
    const float* __restrict__ k_w, const float* __restrict__ k_b,
    const float* __restrict__ q_w, const float* __restrict__ q_b,
    float* __restrict__ km, float* __restrict__ qm) {
  __shared__ unsigned short bsT[16][264];
  int t = threadIdx.x;
  int lane = t & 63;
  int w = t >> 6;
  int px0 = blockIdx.x * 16;
  int b = blockIdx.z;
  int l15 = lane & 15;
  int hi = lane >> 4;

  int oc_a = w * 16 + l15;
  const float* wrow = ((oc_a < CMM) ? (k_w + (size_t)oc_a * CC)
                                    : (q_w + (size_t)(oc_a - CMM) * CC)) + hi * 8;
  bf16x8 ah[8], al[8];
  #pragma unroll
  for (int s = 0; s < 8; ++s) {
    f32x4 w0 = *(const f32x4*)(wrow + s * 32);
    f32x4 w1 = *(const f32x4*)(wrow + s * 32 + 4);
    bf16x8 h, l;
    #pragma unroll
    for (int j = 0; j < 4; ++j) {
      short hb0 = bfr(w0[j]); h[j] = hb0;     l[j] = bfr(w0[j] - bf2f(hb0));
      short hb1 = bfr(w1[j]); h[j + 4] = hb1; l[j + 4] = bfr(w1[j] - bf2f(hb1));
    }
    ah[s] = h; al[s] = l;
  }

  int spx = t & 15;
  int c0s = (t >> 4) * 16;
  const float* xg = x + (size_t)b * CC * LL + px0 + spx;
  float fv[16];
  #pragma unroll
  for (int j = 0; j < 16; ++j) fv[j] = xg[(size_t)(c0s + j) * LL];
  us8_t h0, h1;
  #pragma unroll
  for (int j = 0; j < 8; ++j) {
    h0[j] = (unsigned short)bfr(fv[j]);
    h1[j] = (unsigned short)bfr(fv[8 + j]);
  }
  *(us8_t*)&bsT[spx][c0s]     = h0;
  *(us8_t*)&bsT[spx][c0s + 8] = h1;
  __syncthreads();

  f32x4 acc = {0.f, 0.f, 0.f, 0.f};
  #pragma unroll
  for (int s = 0; s < 8; ++s) {
    bf16x8 bv = *(const bf16x8*)&bsT[l15][s * 32 + hi * 8];
    acc = __builtin_amdgcn_mfma_f32_16x16x32_bf16(ah[s], bv, acc, 0, 0, 0);
    acc = __builtin_amdgcn_mfma_f32_16x16x32_bf16(al[s], bv, acc, 0, 0, 0);
  }
  #pragma unroll
  for (int rr = 0; rr < 4; ++rr) {
    int oc = w * 16 + hi * 4 + rr;
    int px = px0 + l15;
    if (oc < CMM)
      km[((size_t)b * CMM + oc) * LL + px] = acc[rr] + k_b[oc];
    else
      qm[((size_t)b * CMM + (oc - CMM)) * LL + px] = acc[rr] + q_b[oc - CMM];
  }
}

__global__ void __launch_bounds__(256) attn_kernel(
    const float* __restrict__ x, const float* __restrict__ km,
    const float* __restrict__ qm,
    const float* __restrict__ gp_w1, const float* __restrict__ gp_b1,
    const float* __restrict__ gp_w2, const float* __restrict__ gp_b2,
    const float* __restrict__ k_b,
    unsigned short* __restrict__ pre) {
  __shared__ unsigned int xlo[10][64][2];
  __shared__ unsigned int xhi[10][64][2];
  __shared__ float ks[10][64];
  __shared__ float gs2[KK];
  const float LOG2E = 1.44269504f;
  int t = threadIdx.x;
  int cm = blockIdx.y;
  int b = blockIdx.z;
  int y0 = blockIdx.x * 4;

  if (t < KK) {
    int i = t / KW, j = t % KW;
    float xpos = (float)(j - PADW), ypos = (float)(PADW - i);
    float a = gp_b2[cm];
    #pragma unroll
    for (int m = 0; m < MIDW; ++m) {
      float h = fmaxf(gp_w1[2 * m] * xpos + gp_w1[2 * m + 1] * ypos + gp_b1[m], 0.f);
      a = fmaf(gp_w2[cm * MIDW + m], h, a);
    }
    gs2[t] = a * LOG2E;
  }
  float kb_cm = k_b[cm];
  const float* kmb = km + ((size_t)b * CMM + cm) * LL;
  for (int e = t; e < 640; e += 256) {
    int ri = e >> 6, cl = e & 63;
    int rp = y0 + ri;
    bool inner = (rp >= PADW && rp < PADW + HH && cl >= PADW && cl < PADW + WW);
    ks[ri][cl] = inner ? kmb[(rp - PADW) * WW + (cl - PADW)] : kb_cm;
  }
  const float* xg = x + (size_t)b * CC * LL;
  for (int e = t; e < 640; e += 256) {
    int ri = e >> 6, cl = e & 63;
    int ir = y0 - PADW + ri;
    int ic = cl - PADW;
    bool ok = (ir >= 0 && ir < HH && ic >= 0 && ic < WW);
    int off = ok ? (ir * WW + ic) : 0;
    unsigned int pk[4];
    #pragma unroll
    for (int mp = 0; mp < 4; ++mp) {
      float v0 = ok ? xg[(size_t)((2 * mp) * CMM + cm) * LL + off] : 0.f;
      float v1 = ok ? xg[(size_t)((2 * mp + 1) * CMM + cm) * LL + off] : 0.f;
      pk[mp] = (unsigned int)(unsigned short)bfr(v0)
             | ((unsigned int)(unsigned short)bfr(v1) << 16);
    }
    *(uint2*)&xlo[ri][cl][0] = make_uint2(pk[0], pk[1]);
    *(uint2*)&xhi[ri][cl][0] = make_uint2(pk[2], pk[3]);
  }
  __syncthreads();

  int w = t >> 6, c = t & 63;
  int y = y0 + w;
  int ce = (c < WW) ? c : (WW - 1);
  bool act = (c < WW);
  float qc = qm[((size_t)b * CMM + cm) * LL + y * WW + ce] * LOG2E;

  float acc[8] = {0.f, 0.f, 0.f, 0.f, 0.f, 0.f, 0.f, 0.f};
  #pragma unroll
  for (int i = 0; i < KW; ++i) {
    int row = w + i;
    float s[KW];
    float sum = 0.f;
    #pragma unroll
    for (int j = 0; j < KW; ++j) {
      s[j] = exp2f(fmaf(ks[row][ce + j], qc, gs2[i * KW + j]));
      sum += s[j];
    }
    float inv = __builtin_amdgcn_rcpf(sum);
    #pragma unroll
    for (int j = 0; j < KW; ++j) {
      float wj = s[j] * inv;
      uint2 lo2 = *(const uint2*)&xlo[row][ce + j][0];
      uint2 hi2 = *(const uint2*)&xhi[row][ce + j][0];
      acc[0] = fmaf(wj, ubits(lo2.x << 16), acc[0]);
      acc[1] = fmaf(wj, ubits(lo2.x & 0xffff0000u), acc[1]);
      acc[2] = fmaf(wj, ubits(lo2.y << 16), acc[2]);
      acc[3] = fmaf(wj, ubits(lo2.y & 0xffff0000u), acc[3]);
      acc[4] = fmaf(wj, ubits(hi2.x << 16), acc[4]);
      acc[5] = fmaf(wj, ubits(hi2.x & 0xffff0000u), acc[5]);
      acc[6] = fmaf(wj, ubits(hi2.y << 16), acc[6]);
      acc[7] = fmaf(wj, ubits(hi2.y & 0xffff0000u), acc[7]);
    }
  }
  if (act) {
    #pragma unroll
    for (int m = 0; m < 8; ++m)
      pre[((size_t)b * CC + (m * CMM + cm)) * LL + y * WW + c] =
          (unsigned short)bfr(acc[m]);
  }
}

__global__ void __launch_bounds__(256) fconv_kernel(
    const unsigned short* __restrict__ preb,
    const float* __restrict__ f_w, const float* __restrict__ f_b,
    float* __restrict__ out) {
  __shared__ unsigned short bsT[32][264];
  int t = threadIdx.x;
  int lane = t & 63;
  int w = t >> 6;
  int px0 = blockIdx.x * 32;
  int oc0 = blockIdx.y * 64;
  int b = blockIdx.z;
  int l15 = lane & 15;
  int hi = lane >> 4;

  bf16x8 af[8];
  const float* wrow = f_w + (size_t)(oc0 + w * 16 + l15) * CC + hi * 8;
  #pragma unroll
  for (int s = 0; s < 8; ++s) {
    f32x4 w0 = *(const f32x4*)(wrow + s * 32);
    f32x4 w1 = *(const f32x4*)(wrow + s * 32 + 4);
    bf16x8 a;
    #pragma unroll
    for (int j = 0; j < 4; ++j) { a[j] = bfr(w0[j]); a[j + 4] = bfr(w1[j]); }
    af[s] = a;
  }

  int spx = t & 31;
  int c0s = (t >> 5) * 32;
  const unsigned short* pg = preb + (size_t)b * CC * LL + px0 + spx;
  unsigned short uv[32];
  #pragma unroll
  for (int j = 0; j < 32; ++j) uv[j] = pg[(size_t)(c0s + j) * LL];
  #pragma unroll
  for (int qq = 0; qq < 4; ++qq) {
    us8_t hv;
    #pragma unroll
    for (int j = 0; j < 8; ++j) hv[j] = uv[qq * 8 + j];
    *(us8_t*)&bsT[spx][c0s + qq * 8] = hv;
  }
  __syncthreads();

  f32x4 acc[2];
  #pragma unroll
  for (int q = 0; q < 2; ++q) acc[q] = {0.f, 0.f, 0.f, 0.f};
  #pragma unroll
  for (int s = 0; s < 8; ++s) {
    #pragma unroll
    for (int q = 0; q < 2; ++q) {
      bf16x8 bv = *(const bf16x8*)&bsT[q * 16 + l15][s * 32 + hi * 8];
      acc[q] = __builtin_amdgcn_mfma_f32_16x16x32_bf16(af[s], bv, acc[q], 0, 0, 0);
    }
  }
  #pragma unroll
  for (int q = 0; q < 2; ++q) {
    #pragma unroll
    for (int rr = 0; rr < 4; ++rr) {
      int oc = oc0 + w * 16 + hi * 4 + rr;
      out[((size_t)b * CC + oc) * LL + px0 + q * 16 + l15] = acc[q][rr] + f_b[oc];
    }
  }
}

extern "C" void kernel_launch(void* const* d_in, const int* in_sizes, int n_in,
                              void* d_out, int out_size, void* d_ws, size_t ws_size,
                              hipStream_t stream) {
  const float* x     = (const float*)d_in[0];
  const float* k_w   = (const float*)d_in[1];
  const float* k_b   = (const float*)d_in[2];
  const float* q_w   = (const float*)d_in[3];
  const float* q_b   = (const float*)d_in[4];
  const float* gp_w1 = (const float*)d_in[5];
  const float* gp_b1 = (const float*)d_in[6];
  const float* gp_w2 = (const float*)d_in[7];
  const float* gp_b2 = (const float*)d_in[8];
  const float* f_w   = (const float*)d_in[9];
  const float* f_b   = (const float*)d_in[10];
  float* out = (float*)d_out;

  float* ws  = (float*)d_ws;
  float* km  = ws;                                   // 2*32*3136 f32
  float* qm  = km + (size_t)BB * CMM * LL;
  unsigned short* pre = (unsigned short*)(qm + (size_t)BB * CMM * LL); // bf16

  void* args[] = {
    (void*)&x, (void*)&k_w, (void*)&k_b, (void*)&q_w, (void*)&q_b,
    (void*)&gp_w1, (void*)&gp_b1, (void*)&gp_w2, (void*)&gp_b2,
    (void*)&f_w, (void*)&f_b,
    (void*)&km, (void*)&qm, (void*)&pre, (void*)&out,
  };
  hipError_t err = hipLaunchCooperativeKernel((const void*)fused_kernel,
                                              dim3(896, 1, 1), dim3(256, 1, 1),
                                              args, 0, stream);
  if (err != hipSuccess) {
    // deterministic fallback: proven R18 3-kernel path
    hipLaunchKernelGGL(kq_kernel, dim3(LL / 16, 1, BB), dim3(256), 0, stream,
                       x, k_w, k_b, q_w, q_b, km, qm);
    hipLaunchKernelGGL(attn_kernel, dim3(HH / 4, CMM, BB), dim3(256), 0, stream,
                       x, km, qm, gp_w1, gp_b1, gp_w2, gp_b2, k_b, pre);
    hipLaunchKernelGGL(fconv_kernel, dim3(LL / 32, CC / 64, BB), dim3(256), 0, stream,
                       pre, f_w, f_b, out);
  }
}

// Round 22
// 50.763 us; speedup vs baseline: 7.0701x; 7.0701x over previous
//
#include <hip/hip_runtime.h>
#include <hip/hip_bf16.h>

#define CC 256
#define CMM 32
#define KW 7
#define KK 49
#define PADW 3
#define HH 56
#define WW 56
#define LL 3136   // 56*56
#define BB 2
#define MM 8
#define MIDW 16

typedef __attribute__((ext_vector_type(8))) short bf16x8;
typedef __attribute__((ext_vector_type(4))) float f32x4;
typedef __attribute__((ext_vector_type(8))) unsigned short us8_t;

__device__ inline short bfr(float f) {   // f32 -> bf16 bits, RNE
  unsigned int u = __builtin_bit_cast(unsigned int, f);
  u += 0x7fffu + ((u >> 16) & 1u);
  return (short)(u >> 16);
}
__device__ inline float bf2f(short h) {
  return __builtin_bit_cast(float, ((unsigned int)(unsigned short)h) << 16);
}
__device__ inline float ubits(unsigned int u) {
  return __builtin_bit_cast(float, u);
}

// ---------------- k/q 1x1 conv: 16-px tiles, single-phase MFMA (R18) --------
__global__ void __launch_bounds__(256) kq_kernel(
    const float* __restrict__ x,
    const float* __restrict__ k_w, const float* __restrict__ k_b,
    const float* __restrict__ q_w, const float* __restrict__ q_b,
    float* __restrict__ km, float* __restrict__ qm) {
  __shared__ unsigned short bsT[16][264];
  int t = threadIdx.x;
  int lane = t & 63;
  int w = t >> 6;
  int px0 = blockIdx.x * 16;
  int b = blockIdx.z;
  int l15 = lane & 15;
  int hi = lane >> 4;

  int oc_a = w * 16 + l15;
  const float* wrow = ((oc_a < CMM) ? (k_w + (size_t)oc_a * CC)
                                    : (q_w + (size_t)(oc_a - CMM) * CC)) + hi * 8;
  bf16x8 ah[8], al[8];
  #pragma unroll
  for (int s = 0; s < 8; ++s) {
    f32x4 w0 = *(const f32x4*)(wrow + s * 32);
    f32x4 w1 = *(const f32x4*)(wrow + s * 32 + 4);
    bf16x8 h, l;
    #pragma unroll
    for (int j = 0; j < 4; ++j) {
      short hb0 = bfr(w0[j]); h[j] = hb0;     l[j] = bfr(w0[j] - bf2f(hb0));
      short hb1 = bfr(w1[j]); h[j + 4] = hb1; l[j + 4] = bfr(w1[j] - bf2f(hb1));
    }
    ah[s] = h; al[s] = l;
  }

  int spx = t & 15;
  int c0s = (t >> 4) * 16;
  const float* xg = x + (size_t)b * CC * LL + px0 + spx;
  float fv[16];
  #pragma unroll
  for (int j = 0; j < 16; ++j) fv[j] = xg[(size_t)(c0s + j) * LL];
  us8_t h0, h1;
  #pragma unroll
  for (int j = 0; j < 8; ++j) {
    h0[j] = (unsigned short)bfr(fv[j]);
    h1[j] = (unsigned short)bfr(fv[8 + j]);
  }
  *(us8_t*)&bsT[spx][c0s]     = h0;
  *(us8_t*)&bsT[spx][c0s + 8] = h1;
  __syncthreads();

  f32x4 acc = {0.f, 0.f, 0.f, 0.f};
  #pragma unroll
  for (int s = 0; s < 8; ++s) {
    bf16x8 bv = *(const bf16x8*)&bsT[l15][s * 32 + hi * 8];
    acc = __builtin_amdgcn_mfma_f32_16x16x32_bf16(ah[s], bv, acc, 0, 0, 0);
    acc = __builtin_amdgcn_mfma_f32_16x16x32_bf16(al[s], bv, acc, 0, 0, 0);
  }
  #pragma unroll
  for (int rr = 0; rr < 4; ++rr) {
    int oc = w * 16 + hi * 4 + rr;
    int px = px0 + l15;
    if (oc < CMM)
      km[((size_t)b * CMM + oc) * LL + px] = acc[rr] + k_b[oc];
    else
      qm[((size_t)b * CMM + (oc - CMM)) * LL + px] = acc[rr] + q_b[oc - CMM];
  }
}

// ---------------- fused QK * softmax * PV: 1792 blocks, 4 m per block -------
// Grid (14, 64, 2): blockIdx.y = cm*2 + mhalf. Each block stages only its
// 4 m-channels (LDS ~8 KB) -> per-block critical path ~halved vs 896-block
// variants; blocks stay co-resident (7/CU). Softmax dup 2x (parallel work).
__global__ void __launch_bounds__(256) attn_kernel(
    const float* __restrict__ x, const float* __restrict__ km,
    const float* __restrict__ qm,
    const float* __restrict__ gp_w1, const float* __restrict__ gp_b1,
    const float* __restrict__ gp_w2, const float* __restrict__ gp_b2,
    const float* __restrict__ k_b,
    unsigned short* __restrict__ pre) {
  __shared__ unsigned int xpk[10][64][2];  // bf16 pairs (m0,m1),(m2,m3) of mbase
  __shared__ float ks[10][64];
  __shared__ float gs2[KK];
  const float LOG2E = 1.44269504f;
  int t = threadIdx.x;
  int cm = blockIdx.y >> 1;
  int mbase = (blockIdx.y & 1) * 4;
  int b = blockIdx.z;
  int y0 = blockIdx.x * 4;

  if (t < KK) {
    int i = t / KW, j = t % KW;
    float xpos = (float)(j - PADW), ypos = (float)(PADW - i);
    float a = gp_b2[cm];
    #pragma unroll
    for (int m = 0; m < MIDW; ++m) {
      float h = fmaxf(gp_w1[2 * m] * xpos + gp_w1[2 * m + 1] * ypos + gp_b1[m], 0.f);
      a = fmaf(gp_w2[cm * MIDW + m], h, a);
    }
    gs2[t] = a * LOG2E;
  }
  float kb_cm = k_b[cm];
  const float* kmb = km + ((size_t)b * CMM + cm) * LL;
  for (int e = t; e < 640; e += 256) {
    int ri = e >> 6, cl = e & 63;
    int rp = y0 + ri;
    bool inner = (rp >= PADW && rp < PADW + HH && cl >= PADW && cl < PADW + WW);
    ks[ri][cl] = inner ? kmb[(rp - PADW) * WW + (cl - PADW)] : kb_cm;
  }
  const float* xg = x + (size_t)b * CC * LL;
  for (int e = t; e < 640; e += 256) {
    int ri = e >> 6, cl = e & 63;
    int ir = y0 - PADW + ri;
    int ic = cl - PADW;
    bool ok = (ir >= 0 && ir < HH && ic >= 0 && ic < WW);
    int off = ok ? (ir * WW + ic) : 0;
    unsigned int pk[2];
    #pragma unroll
    for (int mp = 0; mp < 2; ++mp) {
      float v0 = ok ? xg[(size_t)((mbase + 2 * mp) * CMM + cm) * LL + off] : 0.f;
      float v1 = ok ? xg[(size_t)((mbase + 2 * mp + 1) * CMM + cm) * LL + off] : 0.f;
      pk[mp] = (unsigned int)(unsigned short)bfr(v0)
             | ((unsigned int)(unsigned short)bfr(v1) << 16);
    }
    *(uint2*)&xpk[ri][cl][0] = make_uint2(pk[0], pk[1]);
  }
  __syncthreads();

  int w = t >> 6, c = t & 63;
  int y = y0 + w;
  int ce = (c < WW) ? c : (WW - 1);
  bool act = (c < WW);
  float qc = qm[((size_t)b * CMM + cm) * LL + y * WW + ce] * LOG2E;

  float acc[4] = {0.f, 0.f, 0.f, 0.f};
  #pragma unroll
  for (int i = 0; i < KW; ++i) {
    int row = w + i;
    float s[KW];
    float sum = 0.f;
    #pragma unroll
    for (int j = 0; j < KW; ++j) {
      s[j] = exp2f(fmaf(ks[row][ce + j], qc, gs2[i * KW + j]));
      sum += s[j];
    }
    float inv = __builtin_amdgcn_rcpf(sum);
    #pragma unroll
    for (int j = 0; j < KW; ++j) {
      float wj = s[j] * inv;
      uint2 p2 = *(const uint2*)&xpk[row][ce + j][0];
      acc[0] = fmaf(wj, ubits(p2.x << 16), acc[0]);
      acc[1] = fmaf(wj, ubits(p2.x & 0xffff0000u), acc[1]);
      acc[2] = fmaf(wj, ubits(p2.y << 16), acc[2]);
      acc[3] = fmaf(wj, ubits(p2.y & 0xffff0000u), acc[3]);
    }
  }
  if (act) {
    #pragma unroll
    for (int mm = 0; mm < 4; ++mm)
      pre[((size_t)b * CC + ((mbase + mm) * CMM + cm)) * LL + y * WW + c] =
          (unsigned short)bfr(acc[mm]);
  }
}

// ---------------- final 1x1 conv: 32-px tiles, single-phase MFMA (R18) ------
__global__ void __launch_bounds__(256) fconv_kernel(
    const unsigned short* __restrict__ preb,
    const float* __restrict__ f_w, const float* __restrict__ f_b,
    float* __restrict__ out) {
  __shared__ unsigned short bsT[32][264];
  int t = threadIdx.x;
  int lane = t & 63;
  int w = t >> 6;
  int px0 = blockIdx.x * 32;
  int oc0 = blockIdx.y * 64;
  int b = blockIdx.z;
  int l15 = lane & 15;
  int hi = lane >> 4;

  bf16x8 af[8];
  const float* wrow = f_w + (size_t)(oc0 + w * 16 + l15) * CC + hi * 8;
  #pragma unroll
  for (int s = 0; s < 8; ++s) {
    f32x4 w0 = *(const f32x4*)(wrow + s * 32);
    f32x4 w1 = *(const f32x4*)(wrow + s * 32 + 4);
    bf16x8 a;
    #pragma unroll
    for (int j = 0; j < 4; ++j) { a[j] = bfr(w0[j]); a[j + 4] = bfr(w1[j]); }
    af[s] = a;
  }

  int spx = t & 31;
  int c0s = (t >> 5) * 32;
  const unsigned short* pg = preb + (size_t)b * CC * LL + px0 + spx;
  unsigned short uv[32];
  #pragma unroll
  for (int j = 0; j < 32; ++j) uv[j] = pg[(size_t)(c0s + j) * LL];
  #pragma unroll
  for (int qq = 0; qq < 4; ++qq) {
    us8_t hv;
    #pragma unroll
    for (int j = 0; j < 8; ++j) hv[j] = uv[qq * 8 + j];
    *(us8_t*)&bsT[spx][c0s + qq * 8] = hv;
  }
  __syncthreads();

  f32x4 acc[2];
  #pragma unroll
  for (int q = 0; q < 2; ++q) acc[q] = {0.f, 0.f, 0.f, 0.f};
  #pragma unroll
  for (int s = 0; s < 8; ++s) {
    #pragma unroll
    for (int q = 0; q < 2; ++q) {
      bf16x8 bv = *(const bf16x8*)&bsT[q * 16 + l15][s * 32 + hi * 8];
      acc[q] = __builtin_amdgcn_mfma_f32_16x16x32_bf16(af[s], bv, acc[q], 0, 0, 0);
    }
  }
  #pragma unroll
  for (int q = 0; q < 2; ++q) {
    #pragma unroll
    for (int rr = 0; rr < 4; ++rr) {
      int oc = oc0 + w * 16 + hi * 4 + rr;
      out[((size_t)b * CC + oc) * LL + px0 + q * 16 + l15] = acc[q][rr] + f_b[oc];
    }
  }
}

extern "C" void kernel_launch(void* const* d_in, const int* in_sizes, int n_in,
                              void* d_out, int out_size, void* d_ws, size_t ws_size,
                              hipStream_t stream) {
  const float* x     = (const float*)d_in[0];
  const float* k_w   = (const float*)d_in[1];
  const float* k_b   = (const float*)d_in[2];
  const float* q_w   = (const float*)d_in[3];
  const float* q_b   = (const float*)d_in[4];
  const float* gp_w1 = (const float*)d_in[5];
  const float* gp_b1 = (const float*)d_in[6];
  const float* gp_w2 = (const float*)d_in[7];
  const float* gp_b2 = (const float*)d_in[8];
  const float* f_w   = (const float*)d_in[9];
  const float* f_b   = (const float*)d_in[10];
  float* out = (float*)d_out;

  float* ws  = (float*)d_ws;
  float* km  = ws;                                   // 2*32*3136 f32
  float* qm  = km + (size_t)BB * CMM * LL;
  unsigned short* pre = (unsigned short*)(qm + (size_t)BB * CMM * LL); // bf16

  hipLaunchKernelGGL(kq_kernel, dim3(LL / 16, 1, BB), dim3(256), 0, stream,
                     x, k_w, k_b, q_w, q_b, km, qm);
  hipLaunchKernelGGL(attn_kernel, dim3(HH / 4, CMM * 2, BB), dim3(256), 0, stream,
                     x, km, qm, gp_w1, gp_b1, gp_w2, gp_b2, k_b, pre);
  hipLaunchKernelGGL(fconv_kernel, dim3(LL / 32, CC / 64, BB), dim3(256), 0, stream,
                     pre, f_w, f_b, out);
}

// Round 23
// 43.106 us; speedup vs baseline: 8.3258x; 1.1776x over previous
//
#include <hip/hip_runtime.h>
#include <hip/hip_bf16.h>

#define CC 256
#define CMM 32
#define KW 7
#define KK 49
#define PADW 3
#define HH 56
#define WW 56
#define LL 3136   // 56*56
#define BB 2
#define MM 8
#define MIDW 16

typedef __attribute__((ext_vector_type(8))) short bf16x8;
typedef __attribute__((ext_vector_type(4))) float f32x4;
typedef __attribute__((ext_vector_type(8))) unsigned short us8_t;

__device__ inline short bfr(float f) {   // f32 -> bf16 bits, RNE
  unsigned int u = __builtin_bit_cast(unsigned int, f);
  u += 0x7fffu + ((u >> 16) & 1u);
  return (short)(u >> 16);
}
__device__ inline float bf2f(short h) {
  return __builtin_bit_cast(float, ((unsigned int)(unsigned short)h) << 16);
}
__device__ inline float ubits(unsigned int u) {
  return __builtin_bit_cast(float, u);
}

// ---------------- k/q 1x1 conv: 16-px tiles, single-phase MFMA (R18) --------
__global__ void __launch_bounds__(256) kq_kernel(
    const float* __restrict__ x,
    const float* __restrict__ k_w, const float* __restrict__ k_b,
    const float* __restrict__ q_w, const float* __restrict__ q_b,
    float* __restrict__ km, float* __restrict__ qm) {
  __shared__ unsigned short bsT[16][264];
  int t = threadIdx.x;
  int lane = t & 63;
  int w = t >> 6;
  int px0 = blockIdx.x * 16;
  int b = blockIdx.z;
  int l15 = lane & 15;
  int hi = lane >> 4;

  int oc_a = w * 16 + l15;
  const float* wrow = ((oc_a < CMM) ? (k_w + (size_t)oc_a * CC)
                                    : (q_w + (size_t)(oc_a - CMM) * CC)) + hi * 8;
  bf16x8 ah[8], al[8];
  #pragma unroll
  for (int s = 0; s < 8; ++s) {
    f32x4 w0 = *(const f32x4*)(wrow + s * 32);
    f32x4 w1 = *(const f32x4*)(wrow + s * 32 + 4);
    bf16x8 h, l;
    #pragma unroll
    for (int j = 0; j < 4; ++j) {
      short hb0 = bfr(w0[j]); h[j] = hb0;     l[j] = bfr(w0[j] - bf2f(hb0));
      short hb1 = bfr(w1[j]); h[j + 4] = hb1; l[j + 4] = bfr(w1[j] - bf2f(hb1));
    }
    ah[s] = h; al[s] = l;
  }

  int spx = t & 15;
  int c0s = (t >> 4) * 16;
  const float* xg = x + (size_t)b * CC * LL + px0 + spx;
  float fv[16];
  #pragma unroll
  for (int j = 0; j < 16; ++j) fv[j] = xg[(size_t)(c0s + j) * LL];
  us8_t h0, h1;
  #pragma unroll
  for (int j = 0; j < 8; ++j) {
    h0[j] = (unsigned short)bfr(fv[j]);
    h1[j] = (unsigned short)bfr(fv[8 + j]);
  }
  *(us8_t*)&bsT[spx][c0s]     = h0;
  *(us8_t*)&bsT[spx][c0s + 8] = h1;
  __syncthreads();

  f32x4 acc = {0.f, 0.f, 0.f, 0.f};
  #pragma unroll
  for (int s = 0; s < 8; ++s) {
    bf16x8 bv = *(const bf16x8*)&bsT[l15][s * 32 + hi * 8];
    acc = __builtin_amdgcn_mfma_f32_16x16x32_bf16(ah[s], bv, acc, 0, 0, 0);
    acc = __builtin_amdgcn_mfma_f32_16x16x32_bf16(al[s], bv, acc, 0, 0, 0);
  }
  #pragma unroll
  for (int rr = 0; rr < 4; ++rr) {
    int oc = w * 16 + hi * 4 + rr;
    int px = px0 + l15;
    if (oc < CMM)
      km[((size_t)b * CMM + oc) * LL + px] = acc[rr] + k_b[oc];
    else
      qm[((size_t)b * CMM + (oc - CMM)) * LL + px] = acc[rr] + q_b[oc - CMM];
  }
}

// ---------------- fused QK * softmax * PV: 448 blocks x 512 thr -------------
// Block covers 8 output rows (window 14 rows). Per-thread code identical to
// R17's 1-px x 8-m form. 4 blocks/CU x 8 waves = 32 waves/CU (max occupancy);
// ramp/tail halved, zero work duplication.
__global__ void __launch_bounds__(512) attn_kernel(
    const float* __restrict__ x, const float* __restrict__ km,
    const float* __restrict__ qm,
    const float* __restrict__ gp_w1, const float* __restrict__ gp_b1,
    const float* __restrict__ gp_w2, const float* __restrict__ gp_b2,
    const float* __restrict__ k_b,
    unsigned short* __restrict__ pre) {
  __shared__ unsigned int xlo[14][64][2];   // bf16 pairs (m0,m1),(m2,m3)
  __shared__ unsigned int xhi[14][64][2];   // (m4,m5),(m6,m7)
  __shared__ float ks[14][64];
  __shared__ float gs2[KK];
  const float LOG2E = 1.44269504f;
  int t = threadIdx.x;
  int cm = blockIdx.y;
  int b = blockIdx.z;
  int y0 = blockIdx.x * 8;

  if (t < KK) {
    int i = t / KW, j = t % KW;
    float xpos = (float)(j - PADW), ypos = (float)(PADW - i);
    float a = gp_b2[cm];
    #pragma unroll
    for (int m = 0; m < MIDW; ++m) {
      float h = fmaxf(gp_w1[2 * m] * xpos + gp_w1[2 * m + 1] * ypos + gp_b1[m], 0.f);
      a = fmaf(gp_w2[cm * MIDW + m], h, a);
    }
    gs2[t] = a * LOG2E;
  }
  float kb_cm = k_b[cm];
  const float* kmb = km + ((size_t)b * CMM + cm) * LL;
  for (int e = t; e < 896; e += 512) {
    int ri = e >> 6, cl = e & 63;
    int rp = y0 + ri;
    bool inner = (rp >= PADW && rp < PADW + HH && cl >= PADW && cl < PADW + WW);
    ks[ri][cl] = inner ? kmb[(rp - PADW) * WW + (cl - PADW)] : kb_cm;
  }
  const float* xg = x + (size_t)b * CC * LL;
  for (int e = t; e < 896; e += 512) {
    int ri = e >> 6, cl = e & 63;
    int ir = y0 - PADW + ri;
    int ic = cl - PADW;
    bool ok = (ir >= 0 && ir < HH && ic >= 0 && ic < WW);
    int off = ok ? (ir * WW + ic) : 0;
    unsigned int pk[4];
    #pragma unroll
    for (int mp = 0; mp < 4; ++mp) {
      float v0 = ok ? xg[(size_t)((2 * mp) * CMM + cm) * LL + off] : 0.f;
      float v1 = ok ? xg[(size_t)((2 * mp + 1) * CMM + cm) * LL + off] : 0.f;
      pk[mp] = (unsigned int)(unsigned short)bfr(v0)
             | ((unsigned int)(unsigned short)bfr(v1) << 16);
    }
    *(uint2*)&xlo[ri][cl][0] = make_uint2(pk[0], pk[1]);
    *(uint2*)&xhi[ri][cl][0] = make_uint2(pk[2], pk[3]);
  }
  __syncthreads();

  int w = t >> 6, c = t & 63;               // w = 0..7 row offset
  int y = y0 + w;
  int ce = (c < WW) ? c : (WW - 1);
  bool act = (c < WW);
  float qc = qm[((size_t)b * CMM + cm) * LL + y * WW + ce] * LOG2E;

  float acc[8] = {0.f, 0.f, 0.f, 0.f, 0.f, 0.f, 0.f, 0.f};
  #pragma unroll
  for (int i = 0; i < KW; ++i) {
    int row = w + i;                        // 0..13
    float s[KW];
    float sum = 0.f;
    #pragma unroll
    for (int j = 0; j < KW; ++j) {
      s[j] = exp2f(fmaf(ks[row][ce + j], qc, gs2[i * KW + j]));
      sum += s[j];
    }
    float inv = __builtin_amdgcn_rcpf(sum);
    #pragma unroll
    for (int j = 0; j < KW; ++j) {
      float wj = s[j] * inv;
      uint2 lo2 = *(const uint2*)&xlo[row][ce + j][0];
      uint2 hi2 = *(const uint2*)&xhi[row][ce + j][0];
      acc[0] = fmaf(wj, ubits(lo2.x << 16), acc[0]);
      acc[1] = fmaf(wj, ubits(lo2.x & 0xffff0000u), acc[1]);
      acc[2] = fmaf(wj, ubits(lo2.y << 16), acc[2]);
      acc[3] = fmaf(wj, ubits(lo2.y & 0xffff0000u), acc[3]);
      acc[4] = fmaf(wj, ubits(hi2.x << 16), acc[4]);
      acc[5] = fmaf(wj, ubits(hi2.x & 0xffff0000u), acc[5]);
      acc[6] = fmaf(wj, ubits(hi2.y << 16), acc[6]);
      acc[7] = fmaf(wj, ubits(hi2.y & 0xffff0000u), acc[7]);
    }
  }
  if (act) {
    #pragma unroll
    for (int m = 0; m < 8; ++m)
      pre[((size_t)b * CC + (m * CMM + cm)) * LL + y * WW + c] =
          (unsigned short)bfr(acc[m]);
  }
}

// ---------------- final 1x1 conv: 32-px tiles, single-phase MFMA (R18) ------
__global__ void __launch_bounds__(256) fconv_kernel(
    const unsigned short* __restrict__ preb,
    const float* __restrict__ f_w, const float* __restrict__ f_b,
    float* __restrict__ out) {
  __shared__ unsigned short bsT[32][264];
  int t = threadIdx.x;
  int lane = t & 63;
  int w = t >> 6;
  int px0 = blockIdx.x * 32;
  int oc0 = blockIdx.y * 64;
  int b = blockIdx.z;
  int l15 = lane & 15;
  int hi = lane >> 4;

  bf16x8 af[8];
  const float* wrow = f_w + (size_t)(oc0 + w * 16 + l15) * CC + hi * 8;
  #pragma unroll
  for (int s = 0; s < 8; ++s) {
    f32x4 w0 = *(const f32x4*)(wrow + s * 32);
    f32x4 w1 = *(const f32x4*)(wrow + s * 32 + 4);
    bf16x8 a;
    #pragma unroll
    for (int j = 0; j < 4; ++j) { a[j] = bfr(w0[j]); a[j + 4] = bfr(w1[j]); }
    af[s] = a;
  }

  int spx = t & 31;
  int c0s = (t >> 5) * 32;
  const unsigned short* pg = preb + (size_t)b * CC * LL + px0 + spx;
  unsigned short uv[32];
  #pragma unroll
  for (int j = 0; j < 32; ++j) uv[j] = pg[(size_t)(c0s + j) * LL];
  #pragma unroll
  for (int qq = 0; qq < 4; ++qq) {
    us8_t hv;
    #pragma unroll
    for (int j = 0; j < 8; ++j) hv[j] = uv[qq * 8 + j];
    *(us8_t*)&bsT[spx][c0s + qq * 8] = hv;
  }
  __syncthreads();

  f32x4 acc[2];
  #pragma unroll
  for (int q = 0; q < 2; ++q) acc[q] = {0.f, 0.f, 0.f, 0.f};
  #pragma unroll
  for (int s = 0; s < 8; ++s) {
    #pragma unroll
    for (int q = 0; q < 2; ++q) {
      bf16x8 bv = *(const bf16x8*)&bsT[q * 16 + l15][s * 32 + hi * 8];
      acc[q] = __builtin_amdgcn_mfma_f32_16x16x32_bf16(af[s], bv, acc[q], 0, 0, 0);
    }
  }
  #pragma unroll
  for (int q = 0; q < 2; ++q) {
    #pragma unroll
    for (int rr = 0; rr < 4; ++rr) {
      int oc = oc0 + w * 16 + hi * 4 + rr;
      out[((size_t)b * CC + oc) * LL + px0 + q * 16 + l15] = acc[q][rr] + f_b[oc];
    }
  }
}

extern "C" void kernel_launch(void* const* d_in, const int* in_sizes, int n_in,
                              void* d_out, int out_size, void* d_ws, size_t ws_size,
                              hipStream_t stream) {
  const float* x     = (const float*)d_in[0];
  const float* k_w   = (const float*)d_in[1];
  const float* k_b   = (const float*)d_in[2];
  const float* q_w   = (const float*)d_in[3];
  const float* q_b   = (const float*)d_in[4];
  const float* gp_w1 = (const float*)d_in[5];
  const float* gp_b1 = (const float*)d_in[6];
  const float* gp_w2 = (const float*)d_in[7];
  const float* gp_b2 = (const float*)d_in[8];
  const float* f_w   = (const float*)d_in[9];
  const float* f_b   = (const float*)d_in[10];
  float* out = (float*)d_out;

  float* ws  = (float*)d_ws;
  float* km  = ws;                                   // 2*32*3136 f32
  float* qm  = km + (size_t)BB * CMM * LL;
  unsigned short* pre = (unsigned short*)(qm + (size_t)BB * CMM * LL); // bf16

  hipLaunchKernelGGL(kq_kernel, dim3(LL / 16, 1, BB), dim3(256), 0, stream,
                     x, k_w, k_b, q_w, q_b, km, qm);
  hipLaunchKernelGGL(attn_kernel, dim3(HH / 8, CMM, BB), dim3(512), 0, stream,
                     x, km, qm, gp_w1, gp_b1, gp_w2, gp_b2, k_b, pre);
  hipLaunchKernelGGL(fconv_kernel, dim3(LL / 32, CC / 64, BB), dim3(256), 0, stream,
                     pre, f_w, f_b, out);
}

// Round 24
// 42.046 us; speedup vs baseline: 8.5358x; 1.0252x over previous
//
#include <hip/hip_runtime.h>
#include <hip/hip_bf16.h>

#define CC 256
#define CMM 32
#define KW 7
#define KK 49
#define PADW 3
#define HH 56
#define WW 56
#define LL 3136   // 56*56
#define BB 2
#define MM 8
#define MIDW 16

typedef __attribute__((ext_vector_type(8))) short bf16x8;
typedef __attribute__((ext_vector_type(4))) float f32x4;
typedef __attribute__((ext_vector_type(8))) unsigned short us8_t;

__device__ inline short bfr(float f) {   // f32 -> bf16 bits, RNE
  unsigned int u = __builtin_bit_cast(unsigned int, f);
  u += 0x7fffu + ((u >> 16) & 1u);
  return (short)(u >> 16);
}
__device__ inline float bf2f(short h) {
  return __builtin_bit_cast(float, ((unsigned int)(unsigned short)h) << 16);
}
__device__ inline float ubits(unsigned int u) {
  return __builtin_bit_cast(float, u);
}

// ---------------- k/q 1x1 conv: 16-px tiles, single-phase MFMA (R18) --------
__global__ void __launch_bounds__(256) kq_kernel(
    const float* __restrict__ x,
    const float* __restrict__ k_w, const float* __restrict__ k_b,
    const float* __restrict__ q_w, const float* __restrict__ q_b,
    float* __restrict__ km, float* __restrict__ qm) {
  __shared__ unsigned short bsT[16][264];
  int t = threadIdx.x;
  int lane = t & 63;
  int w = t >> 6;
  int px0 = blockIdx.x * 16;
  int b = blockIdx.z;
  int l15 = lane & 15;
  int hi = lane >> 4;

  int oc_a = w * 16 + l15;
  const float* wrow = ((oc_a < CMM) ? (k_w + (size_t)oc_a * CC)
                                    : (q_w + (size_t)(oc_a - CMM) * CC)) + hi * 8;
  bf16x8 ah[8], al[8];
  #pragma unroll
  for (int s = 0; s < 8; ++s) {
    f32x4 w0 = *(const f32x4*)(wrow + s * 32);
    f32x4 w1 = *(const f32x4*)(wrow + s * 32 + 4);
    bf16x8 h, l;
    #pragma unroll
    for (int j = 0; j < 4; ++j) {
      short hb0 = bfr(w0[j]); h[j] = hb0;     l[j] = bfr(w0[j] - bf2f(hb0));
      short hb1 = bfr(w1[j]); h[j + 4] = hb1; l[j + 4] = bfr(w1[j] - bf2f(hb1));
    }
    ah[s] = h; al[s] = l;
  }

  int spx = t & 15;
  int c0s = (t >> 4) * 16;
  const float* xg = x + (size_t)b * CC * LL + px0 + spx;
  float fv[16];
  #pragma unroll
  for (int j = 0; j < 16; ++j) fv[j] = xg[(size_t)(c0s + j) * LL];
  us8_t h0, h1;
  #pragma unroll
  for (int j = 0; j < 8; ++j) {
    h0[j] = (unsigned short)bfr(fv[j]);
    h1[j] = (unsigned short)bfr(fv[8 + j]);
  }
  *(us8_t*)&bsT[spx][c0s]     = h0;
  *(us8_t*)&bsT[spx][c0s + 8] = h1;
  __syncthreads();

  f32x4 acc = {0.f, 0.f, 0.f, 0.f};
  #pragma unroll
  for (int s = 0; s < 8; ++s) {
    bf16x8 bv = *(const bf16x8*)&bsT[l15][s * 32 + hi * 8];
    acc = __builtin_amdgcn_mfma_f32_16x16x32_bf16(ah[s], bv, acc, 0, 0, 0);
    acc = __builtin_amdgcn_mfma_f32_16x16x32_bf16(al[s], bv, acc, 0, 0, 0);
  }
  #pragma unroll
  for (int rr = 0; rr < 4; ++rr) {
    int oc = w * 16 + hi * 4 + rr;
    int px = px0 + l15;
    if (oc < CMM)
      km[((size_t)b * CMM + oc) * LL + px] = acc[rr] + k_b[oc];
    else
      qm[((size_t)b * CMM + (oc - CMM)) * LL + px] = acc[rr] + q_b[oc - CMM];
  }
}

// ---------------- fused QK * softmax * PV: 448 blocks x 512 thr -------------
// R23 structure; softmax via __expf (fast intrinsic -> v_exp_f32), NOT the
// precise libm exp2f that was silently costing ~20+ VALU ops per exp.
__global__ void __launch_bounds__(512) attn_kernel(
    const float* __restrict__ x, const float* __restrict__ km,
    const float* __restrict__ qm,
    const float* __restrict__ gp_w1, const float* __restrict__ gp_b1,
    const float* __restrict__ gp_w2, const float* __restrict__ gp_b2,
    const float* __restrict__ k_b,
    unsigned short* __restrict__ pre) {
  __shared__ unsigned int xlo[14][64][2];   // bf16 pairs (m0,m1),(m2,m3)
  __shared__ unsigned int xhi[14][64][2];   // (m4,m5),(m6,m7)
  __shared__ float ks[14][64];
  __shared__ float gs2[KK];
  int t = threadIdx.x;
  int cm = blockIdx.y;
  int b = blockIdx.z;
  int y0 = blockIdx.x * 8;

  if (t < KK) {
    int i = t / KW, j = t % KW;
    float xpos = (float)(j - PADW), ypos = (float)(PADW - i);
    float a = gp_b2[cm];
    #pragma unroll
    for (int m = 0; m < MIDW; ++m) {
      float h = fmaxf(gp_w1[2 * m] * xpos + gp_w1[2 * m + 1] * ypos + gp_b1[m], 0.f);
      a = fmaf(gp_w2[cm * MIDW + m], h, a);
    }
    gs2[t] = a;                     // natural-log domain
  }
  float kb_cm = k_b[cm];
  const float* kmb = km + ((size_t)b * CMM + cm) * LL;
  for (int e = t; e < 896; e += 512) {
    int ri = e >> 6, cl = e & 63;
    int rp = y0 + ri;
    bool inner = (rp >= PADW && rp < PADW + HH && cl >= PADW && cl < PADW + WW);
    ks[ri][cl] = inner ? kmb[(rp - PADW) * WW + (cl - PADW)] : kb_cm;
  }
  const float* xg = x + (size_t)b * CC * LL;
  for (int e = t; e < 896; e += 512) {
    int ri = e >> 6, cl = e & 63;
    int ir = y0 - PADW + ri;
    int ic = cl - PADW;
    bool ok = (ir >= 0 && ir < HH && ic >= 0 && ic < WW);
    int off = ok ? (ir * WW + ic) : 0;
    unsigned int pk[4];
    #pragma unroll
    for (int mp = 0; mp < 4; ++mp) {
      float v0 = ok ? xg[(size_t)((2 * mp) * CMM + cm) * LL + off] : 0.f;
      float v1 = ok ? xg[(size_t)((2 * mp + 1) * CMM + cm) * LL + off] : 0.f;
      pk[mp] = (unsigned int)(unsigned short)bfr(v0)
             | ((unsigned int)(unsigned short)bfr(v1) << 16);
    }
    *(uint2*)&xlo[ri][cl][0] = make_uint2(pk[0], pk[1]);
    *(uint2*)&xhi[ri][cl][0] = make_uint2(pk[2], pk[3]);
  }
  __syncthreads();

  int w = t >> 6, c = t & 63;               // w = 0..7 row offset
  int y = y0 + w;
  int ce = (c < WW) ? c : (WW - 1);
  bool act = (c < WW);
  float qc = qm[((size_t)b * CMM + cm) * LL + y * WW + ce];

  float acc[8] = {0.f, 0.f, 0.f, 0.f, 0.f, 0.f, 0.f, 0.f};
  #pragma unroll
  for (int i = 0; i < KW; ++i) {
    int row = w + i;                        // 0..13
    float s[KW];
    float sum = 0.f;
    #pragma unroll
    for (int j = 0; j < KW; ++j) {
      s[j] = __expf(fmaf(ks[row][ce + j], qc, gs2[i * KW + j]));
      sum += s[j];
    }
    float inv = __builtin_amdgcn_rcpf(sum);
    #pragma unroll
    for (int j = 0; j < KW; ++j) {
      float wj = s[j] * inv;
      uint2 lo2 = *(const uint2*)&xlo[row][ce + j][0];
      uint2 hi2 = *(const uint2*)&xhi[row][ce + j][0];
      acc[0] = fmaf(wj, ubits(lo2.x << 16), acc[0]);
      acc[1] = fmaf(wj, ubits(lo2.x & 0xffff0000u), acc[1]);
      acc[2] = fmaf(wj, ubits(lo2.y << 16), acc[2]);
      acc[3] = fmaf(wj, ubits(lo2.y & 0xffff0000u), acc[3]);
      acc[4] = fmaf(wj, ubits(hi2.x << 16), acc[4]);
      acc[5] = fmaf(wj, ubits(hi2.x & 0xffff0000u), acc[5]);
      acc[6] = fmaf(wj, ubits(hi2.y << 16), acc[6]);
      acc[7] = fmaf(wj, ubits(hi2.y & 0xffff0000u), acc[7]);
    }
  }
  if (act) {
    #pragma unroll
    for (int m = 0; m < 8; ++m)
      pre[((size_t)b * CC + (m * CMM + cm)) * LL + y * WW + c] =
          (unsigned short)bfr(acc[m]);
  }
}

// ---------------- final 1x1 conv: 32-px tiles, single-phase MFMA (R18) ------
__global__ void __launch_bounds__(256) fconv_kernel(
    const unsigned short* __restrict__ preb,
    const float* __restrict__ f_w, const float* __restrict__ f_b,
    float* __restrict__ out) {
  __shared__ unsigned short bsT[32][264];
  int t = threadIdx.x;
  int lane = t & 63;
  int w = t >> 6;
  int px0 = blockIdx.x * 32;
  int oc0 = blockIdx.y * 64;
  int b = blockIdx.z;
  int l15 = lane & 15;
  int hi = lane >> 4;

  bf16x8 af[8];
  const float* wrow = f_w + (size_t)(oc0 + w * 16 + l15) * CC + hi * 8;
  #pragma unroll
  for (int s = 0; s < 8; ++s) {
    f32x4 w0 = *(const f32x4*)(wrow + s * 32);
    f32x4 w1 = *(const f32x4*)(wrow + s * 32 + 4);
    bf16x8 a;
    #pragma unroll
    for (int j = 0; j < 4; ++j) { a[j] = bfr(w0[j]); a[j + 4] = bfr(w1[j]); }
    af[s] = a;
  }

  int spx = t & 31;
  int c0s = (t >> 5) * 32;
  const unsigned short* pg = preb + (size_t)b * CC * LL + px0 + spx;
  unsigned short uv[32];
  #pragma unroll
  for (int j = 0; j < 32; ++j) uv[j] = pg[(size_t)(c0s + j) * LL];
  #pragma unroll
  for (int qq = 0; qq < 4; ++qq) {
    us8_t hv;
    #pragma unroll
    for (int j = 0; j < 8; ++j) hv[j] = uv[qq * 8 + j];
    *(us8_t*)&bsT[spx][c0s + qq * 8] = hv;
  }
  __syncthreads();

  f32x4 acc[2];
  #pragma unroll
  for (int q = 0; q < 2; ++q) acc[q] = {0.f, 0.f, 0.f, 0.f};
  #pragma unroll
  for (int s = 0; s < 8; ++s) {
    #pragma unroll
    for (int q = 0; q < 2; ++q) {
      bf16x8 bv = *(const bf16x8*)&bsT[q * 16 + l15][s * 32 + hi * 8];
      acc[q] = __builtin_amdgcn_mfma_f32_16x16x32_bf16(af[s], bv, acc[q], 0, 0, 0);
    }
  }
  #pragma unroll
  for (int q = 0; q < 2; ++q) {
    #pragma unroll
    for (int rr = 0; rr < 4; ++rr) {
      int oc = oc0 + w * 16 + hi * 4 + rr;
      out[((size_t)b * CC + oc) * LL + px0 + q * 16 + l15] = acc[q][rr] + f_b[oc];
    }
  }
}

extern "C" void kernel_launch(void* const* d_in, const int* in_sizes, int n_in,
                              void* d_out, int out_size, void* d_ws, size_t ws_size,
                              hipStream_t stream) {
  const float* x     = (const float*)d_in[0];
  const float* k_w   = (const float*)d_in[1];
  const float* k_b   = (const float*)d_in[2];
  const float* q_w   = (const float*)d_in[3];
  const float* q_b   = (const float*)d_in[4];
  const float* gp_w1 = (const float*)d_in[5];
  const float* gp_b1 = (const float*)d_in[6];
  const float* gp_w2 = (const float*)d_in[7];
  const float* gp_b2 = (const float*)d_in[8];
  const float* f_w   = (const float*)d_in[9];
  const float* f_b   = (const float*)d_in[10];
  float* out = (float*)d_out;

  float* ws  = (float*)d_ws;
  float* km  = ws;                                   // 2*32*3136 f32
  float* qm  = km + (size_t)BB * CMM * LL;
  unsigned short* pre = (unsigned short*)(qm + (size_t)BB * CMM * LL); // bf16

  hipLaunchKernelGGL(kq_kernel, dim3(LL / 16, 1, BB), dim3(256), 0, stream,
                     x, k_w, k_b, q_w, q_b, km, qm);
  hipLaunchKernelGGL(attn_kernel, dim3(HH / 8, CMM, BB), dim3(512), 0, stream,
                     x, km, qm, gp_w1, gp_b1, gp_w2, gp_b2, k_b, pre);
  hipLaunchKernelGGL(fconv_kernel, dim3(LL / 32, CC / 64, BB), dim3(256), 0, stream,
                     pre, f_w, f_b, out);
}

// Round 25
// 40.547 us; speedup vs baseline: 8.8514x; 1.0370x over previous
//
#include <hip/hip_runtime.h>
#include <hip/hip_bf16.h>

#define CC 256
#define CMM 32
#define KW 7
#define KK 49
#define PADW 3
#define HH 56
#define WW 56
#define LL 3136   // 56*56
#define BB 2
#define MM 8
#define MIDW 16

typedef __attribute__((ext_vector_type(8))) short bf16x8;
typedef __attribute__((ext_vector_type(4))) float f32x4;
typedef __attribute__((ext_vector_type(2))) float f32x2;
typedef __attribute__((ext_vector_type(8))) unsigned short us8_t;

__device__ inline short bfr(float f) {   // f32 -> bf16 bits, RNE
  unsigned int u = __builtin_bit_cast(unsigned int, f);
  u += 0x7fffu + ((u >> 16) & 1u);
  return (short)(u >> 16);
}
__device__ inline float bf2f(short h) {
  return __builtin_bit_cast(float, ((unsigned int)(unsigned short)h) << 16);
}
__device__ inline float ubits(unsigned int u) {
  return __builtin_bit_cast(float, u);
}
__device__ inline float fexp2(float a) {  // direct v_exp_f32: D = 2^S0
  float r;
  asm("v_exp_f32 %0, %1" : "=v"(r) : "v"(a));
  return r;
}

// ---------------- k/q 1x1 conv: 16-px tiles, single-phase MFMA (R18) --------
__global__ void __launch_bounds__(256) kq_kernel(
    const float* __restrict__ x,
    const float* __restrict__ k_w, const float* __restrict__ k_b,
    const float* __restrict__ q_w, const float* __restrict__ q_b,
    float* __restrict__ km, float* __restrict__ qm) {
  __shared__ unsigned short bsT[16][264];
  int t = threadIdx.x;
  int lane = t & 63;
  int w = t >> 6;
  int px0 = blockIdx.x * 16;
  int b = blockIdx.z;
  int l15 = lane & 15;
  int hi = lane >> 4;

  int oc_a = w * 16 + l15;
  const float* wrow = ((oc_a < CMM) ? (k_w + (size_t)oc_a * CC)
                                    : (q_w + (size_t)(oc_a - CMM) * CC)) + hi * 8;
  bf16x8 ah[8], al[8];
  #pragma unroll
  for (int s = 0; s < 8; ++s) {
    f32x4 w0 = *(const f32x4*)(wrow + s * 32);
    f32x4 w1 = *(const f32x4*)(wrow + s * 32 + 4);
    bf16x8 h, l;
    #pragma unroll
    for (int j = 0; j < 4; ++j) {
      short hb0 = bfr(w0[j]); h[j] = hb0;     l[j] = bfr(w0[j] - bf2f(hb0));
      short hb1 = bfr(w1[j]); h[j + 4] = hb1; l[j + 4] = bfr(w1[j] - bf2f(hb1));
    }
    ah[s] = h; al[s] = l;
  }

  int spx = t & 15;
  int c0s = (t >> 4) * 16;
  const float* xg = x + (size_t)b * CC * LL + px0 + spx;
  float fv[16];
  #pragma unroll
  for (int j = 0; j < 16; ++j) fv[j] = xg[(size_t)(c0s + j) * LL];
  us8_t h0, h1;
  #pragma unroll
  for (int j = 0; j < 8; ++j) {
    h0[j] = (unsigned short)bfr(fv[j]);
    h1[j] = (unsigned short)bfr(fv[8 + j]);
  }
  *(us8_t*)&bsT[spx][c0s]     = h0;
  *(us8_t*)&bsT[spx][c0s + 8] = h1;
  __syncthreads();

  f32x4 acc = {0.f, 0.f, 0.f, 0.f};
  #pragma unroll
  for (int s = 0; s < 8; ++s) {
    bf16x8 bv = *(const bf16x8*)&bsT[l15][s * 32 + hi * 8];
    acc = __builtin_amdgcn_mfma_f32_16x16x32_bf16(ah[s], bv, acc, 0, 0, 0);
    acc = __builtin_amdgcn_mfma_f32_16x16x32_bf16(al[s], bv, acc, 0, 0, 0);
  }
  #pragma unroll
  for (int rr = 0; rr < 4; ++rr) {
    int oc = w * 16 + hi * 4 + rr;
    int px = px0 + l15;
    if (oc < CMM)
      km[((size_t)b * CMM + oc) * LL + px] = acc[rr] + k_b[oc];
    else
      qm[((size_t)b * CMM + (oc - CMM)) * LL + px] = acc[rr] + q_b[oc - CMM];
  }
}

// ---------------- fused QK * softmax * PV: 448 blocks x 512 thr -------------
// R23 structure + LOG2E-prefold softmax via direct v_exp_f32 + packed-f32
// (v_pk_fma_f32) PV accumulation on m-pairs.
__global__ void __launch_bounds__(512) attn_kernel(
    const float* __restrict__ x, const float* __restrict__ km,
    const float* __restrict__ qm,
    const float* __restrict__ gp_w1, const float* __restrict__ gp_b1,
    const float* __restrict__ gp_w2, const float* __restrict__ gp_b2,
    const float* __restrict__ k_b,
    unsigned short* __restrict__ pre) {
  __shared__ unsigned int xlo[14][64][2];   // bf16 pairs (m0,m1),(m2,m3)
  __shared__ unsigned int xhi[14][64][2];   // (m4,m5),(m6,m7)
  __shared__ float ks[14][64];
  __shared__ float gs2[KK];
  const float LOG2E = 1.44269504f;
  int t = threadIdx.x;
  int cm = blockIdx.y;
  int b = blockIdx.z;
  int y0 = blockIdx.x * 8;

  if (t < KK) {
    int i = t / KW, j = t % KW;
    float xpos = (float)(j - PADW), ypos = (float)(PADW - i);
    float a = gp_b2[cm];
    #pragma unroll
    for (int m = 0; m < MIDW; ++m) {
      float h = fmaxf(gp_w1[2 * m] * xpos + gp_w1[2 * m + 1] * ypos + gp_b1[m], 0.f);
      a = fmaf(gp_w2[cm * MIDW + m], h, a);
    }
    gs2[t] = a * LOG2E;               // log2 domain
  }
  float kb_cm = k_b[cm];
  const float* kmb = km + ((size_t)b * CMM + cm) * LL;
  for (int e = t; e < 896; e += 512) {
    int ri = e >> 6, cl = e & 63;
    int rp = y0 + ri;
    bool inner = (rp >= PADW && rp < PADW + HH && cl >= PADW && cl < PADW + WW);
    ks[ri][cl] = inner ? kmb[(rp - PADW) * WW + (cl - PADW)] : kb_cm;
  }
  const float* xg = x + (size_t)b * CC * LL;
  for (int e = t; e < 896; e += 512) {
    int ri = e >> 6, cl = e & 63;
    int ir = y0 - PADW + ri;
    int ic = cl - PADW;
    bool ok = (ir >= 0 && ir < HH && ic >= 0 && ic < WW);
    int off = ok ? (ir * WW + ic) : 0;
    unsigned int pk[4];
    #pragma unroll
    for (int mp = 0; mp < 4; ++mp) {
      float v0 = ok ? xg[(size_t)((2 * mp) * CMM + cm) * LL + off] : 0.f;
      float v1 = ok ? xg[(size_t)((2 * mp + 1) * CMM + cm) * LL + off] : 0.f;
      pk[mp] = (unsigned int)(unsigned short)bfr(v0)
             | ((unsigned int)(unsigned short)bfr(v1) << 16);
    }
    *(uint2*)&xlo[ri][cl][0] = make_uint2(pk[0], pk[1]);
    *(uint2*)&xhi[ri][cl][0] = make_uint2(pk[2], pk[3]);
  }
  __syncthreads();

  int w = t >> 6, c = t & 63;               // w = 0..7 row offset
  int y = y0 + w;
  int ce = (c < WW) ? c : (WW - 1);
  bool act = (c < WW);
  float qc = qm[((size_t)b * CMM + cm) * LL + y * WW + ce] * LOG2E;

  f32x2 acc2[4];
  #pragma unroll
  for (int m = 0; m < 4; ++m) acc2[m] = {0.f, 0.f};

  #pragma unroll
  for (int i = 0; i < KW; ++i) {
    int row = w + i;                        // 0..13
    float s[KW];
    float sum = 0.f;
    #pragma unroll
    for (int j = 0; j < KW; ++j) {
      s[j] = fexp2(fmaf(ks[row][ce + j], qc, gs2[i * KW + j]));
      sum += s[j];
    }
    float inv = __builtin_amdgcn_rcpf(sum);
    #pragma unroll
    for (int j = 0; j < KW; ++j) {
      float wj = s[j] * inv;
      uint2 lo2 = *(const uint2*)&xlo[row][ce + j][0];
      uint2 hi2 = *(const uint2*)&xhi[row][ce + j][0];
      f32x2 x01 = {ubits(lo2.x << 16), ubits(lo2.x & 0xffff0000u)};
      f32x2 x23 = {ubits(lo2.y << 16), ubits(lo2.y & 0xffff0000u)};
      f32x2 x45 = {ubits(hi2.x << 16), ubits(hi2.x & 0xffff0000u)};
      f32x2 x67 = {ubits(hi2.y << 16), ubits(hi2.y & 0xffff0000u)};
      acc2[0] += wj * x01;                  // v_pk_fma_f32
      acc2[1] += wj * x23;
      acc2[2] += wj * x45;
      acc2[3] += wj * x67;
    }
  }
  if (act) {
    #pragma unroll
    for (int mp = 0; mp < 4; ++mp) {
      pre[((size_t)b * CC + ((2 * mp) * CMM + cm)) * LL + y * WW + c] =
          (unsigned short)bfr(acc2[mp][0]);
      pre[((size_t)b * CC + ((2 * mp + 1) * CMM + cm)) * LL + y * WW + c] =
          (unsigned short)bfr(acc2[mp][1]);
    }
  }
}

// ---------------- final 1x1 conv: 32-px tiles, single-phase MFMA (R18) ------
__global__ void __launch_bounds__(256) fconv_kernel(
    const unsigned short* __restrict__ preb,
    const float* __restrict__ f_w, const float* __restrict__ f_b,
    float* __restrict__ out) {
  __shared__ unsigned short bsT[32][264];
  int t = threadIdx.x;
  int lane = t & 63;
  int w = t >> 6;
  int px0 = blockIdx.x * 32;
  int oc0 = blockIdx.y * 64;
  int b = blockIdx.z;
  int l15 = lane & 15;
  int hi = lane >> 4;

  bf16x8 af[8];
  const float* wrow = f_w + (size_t)(oc0 + w * 16 + l15) * CC + hi * 8;
  #pragma unroll
  for (int s = 0; s < 8; ++s) {
    f32x4 w0 = *(const f32x4*)(wrow + s * 32);
    f32x4 w1 = *(const f32x4*)(wrow + s * 32 + 4);
    bf16x8 a;
    #pragma unroll
    for (int j = 0; j < 4; ++j) { a[j] = bfr(w0[j]); a[j + 4] = bfr(w1[j]); }
    af[s] = a;
  }

  int spx = t & 31;
  int c0s = (t >> 5) * 32;
  const unsigned short* pg = preb + (size_t)b * CC * LL + px0 + spx;
  unsigned short uv[32];
  #pragma unroll
  for (int j = 0; j < 32; ++j) uv[j] = pg[(size_t)(c0s + j) * LL];
  #pragma unroll
  for (int qq = 0; qq < 4; ++qq) {
    us8_t hv;
    #pragma unroll
    for (int j = 0; j < 8; ++j) hv[j] = uv[qq * 8 + j];
    *(us8_t*)&bsT[spx][c0s + qq * 8] = hv;
  }
  __syncthreads();

  f32x4 acc[2];
  #pragma unroll
  for (int q = 0; q < 2; ++q) acc[q] = {0.f, 0.f, 0.f, 0.f};
  #pragma unroll
  for (int s = 0; s < 8; ++s) {
    #pragma unroll
    for (int q = 0; q < 2; ++q) {
      bf16x8 bv = *(const bf16x8*)&bsT[q * 16 + l15][s * 32 + hi * 8];
      acc[q] = __builtin_amdgcn_mfma_f32_16x16x32_bf16(af[s], bv, acc[q], 0, 0, 0);
    }
  }
  #pragma unroll
  for (int q = 0; q < 2; ++q) {
    #pragma unroll
    for (int rr = 0; rr < 4; ++rr) {
      int oc = oc0 + w * 16 + hi * 4 + rr;
      out[((size_t)b * CC + oc) * LL + px0 + q * 16 + l15] = acc[q][rr] + f_b[oc];
    }
  }
}

extern "C" void kernel_launch(void* const* d_in, const int* in_sizes, int n_in,
                              void* d_out, int out_size, void* d_ws, size_t ws_size,
                              hipStream_t stream) {
  const float* x     = (const float*)d_in[0];
  const float* k_w   = (const float*)d_in[1];
  const float* k_b   = (const float*)d_in[2];
  const float* q_w   = (const float*)d_in[3];
  const float* q_b   = (const float*)d_in[4];
  const float* gp_w1 = (const float*)d_in[5];
  const float* gp_b1 = (const float*)d_in[6];
  const float* gp_w2 = (const float*)d_in[7];
  const float* gp_b2 = (const float*)d_in[8];
  const float* f_w   = (const float*)d_in[9];
  const float* f_b   = (const float*)d_in[10];
  float* out = (float*)d_out;

  float* ws  = (float*)d_ws;
  float* km  = ws;                                   // 2*32*3136 f32
  float* qm  = km + (size_t)BB * CMM * LL;
  unsigned short* pre = (unsigned short*)(qm + (size_t)BB * CMM * LL); // bf16

  hipLaunchKernelGGL(kq_kernel, dim3(LL / 16, 1, BB), dim3(256), 0, stream,
                     x, k_w, k_b, q_w, q_b, km, qm);
  hipLaunchKernelGGL(attn_kernel, dim3(HH / 8, CMM, BB), dim3(512), 0, stream,
                     x, km, qm, gp_w1, gp_b1, gp_w2, gp_b2, k_b, pre);
  hipLaunchKernelGGL(fconv_kernel, dim3(LL / 32, CC / 64, BB), dim3(256), 0, stream,
                     pre, f_w, f_b, out);
}